// Round 14
// baseline (464.535 us; speedup 1.0000x reference)
//
#include <hip/hip_runtime.h>
#include <math.h>

typedef __bf16 bf16x8 __attribute__((ext_vector_type(8)));
typedef __bf16 bf16x4 __attribute__((ext_vector_type(4)));
typedef __bf16 bf16x2 __attribute__((ext_vector_type(2)));
typedef float  f32x4  __attribute__((ext_vector_type(4)));

#define DEV __device__ __forceinline__

DEV void gload16(const void* g, void* l) {
  __builtin_amdgcn_global_load_lds(
      (const __attribute__((address_space(1))) void*)g,
      (__attribute__((address_space(3))) void*)l, 16, 0, 0);
}

// ---------------------------------------------------------------------------
// All four weight transposes in ONE launch. f32 [R][C] -> bf16 [C][R],
// 64x64 tiles, float4 reads / bf16x8 writes. Flat grid 8192 blocks.
// ---------------------------------------------------------------------------
__global__ __launch_bounds__(256) void transpose_cvt_all(
    const float* __restrict__ w_qkv, const float* __restrict__ w_out,
    const float* __restrict__ w_fc, const float* __restrict__ w_proj,
    __bf16* __restrict__ o_qkv, __bf16* __restrict__ o_out,
    __bf16* __restrict__ o_fc, __bf16* __restrict__ o_proj) {
  const int bid = blockIdx.x;
  const float* in;
  __bf16* outT;
  int R, C, bx, by;
  if (bid < 3072) {
    in = w_qkv; outT = o_qkv; R = 2048; C = 6144;
    bx = bid % 96; by = bid / 96;
  } else if (bid < 4096) {
    in = w_out; outT = o_out; R = 2048; C = 2048;
    int l = bid - 3072; bx = l & 31; by = l >> 5;
  } else if (bid < 6144) {
    in = w_fc; outT = o_fc; R = 2048; C = 4096;
    int l = bid - 4096; bx = l & 63; by = l >> 6;
  } else {
    in = w_proj; outT = o_proj; R = 4096; C = 2048;
    int l = bid - 6144; bx = l & 31; by = l >> 5;
  }
  __shared__ float t[64][65];
  const int c0 = bx * 64, r0 = by * 64;
  const int tid = threadIdx.x;
#pragma unroll
  for (int i = 0; i < 4; i++) {
    int r = (tid >> 4) + i * 16;
    int cf = tid & 15;
    float4 v = *(const float4*)(in + (size_t)(r0 + r) * C + c0 + cf * 4);
    t[r][cf * 4 + 0] = v.x; t[r][cf * 4 + 1] = v.y;
    t[r][cf * 4 + 2] = v.z; t[r][cf * 4 + 3] = v.w;
  }
  __syncthreads();
#pragma unroll
  for (int i = 0; i < 2; i++) {
    int c = (tid >> 3) + i * 32;
    int r8 = tid & 7;
    bf16x8 ov;
#pragma unroll
    for (int k = 0; k < 8; k++) ov[k] = (__bf16)t[r8 * 8 + k][c];
    *(bf16x8*)(outT + (size_t)(c0 + c) * R + r0 + r8 * 8) = ov;
  }
}

// ---------------------------------------------------------------------------
// RMSNorm row kernel: f32 [rows][2048] -> bf16, 1 block/row, 8 elems/thread.
// ---------------------------------------------------------------------------
__global__ __launch_bounds__(256) void rmsnorm_kernel(
    const float* __restrict__ x, const float* __restrict__ g, __bf16* __restrict__ out) {
  const int r = blockIdx.x, t = threadIdx.x;
  const float4* xr = (const float4*)(x + (size_t)r * 2048);
  float4 a = xr[2 * t], b = xr[2 * t + 1];
  float ss = a.x * a.x + a.y * a.y + a.z * a.z + a.w * a.w +
             b.x * b.x + b.y * b.y + b.z * b.z + b.w * b.w;
#pragma unroll
  for (int mk = 1; mk < 64; mk <<= 1) ss += __shfl_xor(ss, mk);
  __shared__ float red[4];
  if ((t & 63) == 0) red[t >> 6] = ss;
  __syncthreads();
  const float sc = rsqrtf((red[0] + red[1] + red[2] + red[3]) * (1.0f / 2048.0f) + 1e-6f);
  const float4* gr = (const float4*)g;
  float4 ga = gr[2 * t], gb = gr[2 * t + 1];
  bf16x8 ov;
  ov[0] = (__bf16)(a.x * sc * ga.x); ov[1] = (__bf16)(a.y * sc * ga.y);
  ov[2] = (__bf16)(a.z * sc * ga.z); ov[3] = (__bf16)(a.w * sc * ga.w);
  ov[4] = (__bf16)(b.x * sc * gb.x); ov[5] = (__bf16)(b.y * sc * gb.y);
  ov[6] = (__bf16)(b.z * sc * gb.z); ov[7] = (__bf16)(b.w * sc * gb.w);
  *(bf16x8*)(out + (size_t)r * 2048 + t * 8) = ov;
}

// ---------------------------------------------------------------------------
// QKV GEMM with fused RoPE + head-split + V-transpose epilogue.
// R10 proven version: direct stores, on-the-fly cos/sin (revolutions domain),
// pair-store bf16x2 on even lanes.
// ---------------------------------------------------------------------------
__global__ __launch_bounds__(256, 6) void gemm_qkv(
    const __bf16* __restrict__ A, const __bf16* __restrict__ BT,
    __bf16* __restrict__ qr, __bf16* __restrict__ kr, __bf16* __restrict__ vt,
    int K) {
  __shared__ char lds[32768];
  char* As = lds;
  char* Bs = lds + 16384;
  const int tid = threadIdx.x;
  const int lane = tid & 63;
  const int bn = blockIdx.x, bm = blockIdx.y;
  const int wm = tid >> 7, wn = (tid >> 6) & 1;

  f32x4 acc[4][4];
#pragma unroll
  for (int i = 0; i < 4; i++)
#pragma unroll
    for (int j = 0; j < 4; j++) acc[i][j] = (f32x4){0.f, 0.f, 0.f, 0.f};

  const size_t strideA = (size_t)K * 2;
  const char* ga[4];
  const char* gb[4];
#pragma unroll
  for (int t = 0; t < 4; t++) {
    int gg = t * 256 + tid;
    int row = gg >> 3, slot = gg & 7;
    ga[t] = (const char*)A + (size_t)(bm * 128 + row) * strideA + ((slot ^ (row & 7)) << 4);
    gb[t] = (const char*)BT + (size_t)(bn * 128 + row) * strideA + ((slot ^ (row & 7)) << 4);
  }

  for (int k0 = 0; k0 < K; k0 += 64) {
    __syncthreads();
#pragma unroll
    for (int t = 0; t < 4; t++) {
      int gg = t * 256 + tid;
      gload16(ga[t], As + gg * 16);
      gload16(gb[t], Bs + gg * 16);
      ga[t] += 128;
      gb[t] += 128;
    }
    __syncthreads();
#pragma unroll
    for (int kk = 0; kk < 2; kk++) {
      bf16x8 a[4], b[4];
      const int c16 = kk * 4 + (lane >> 4);
#pragma unroll
      for (int i = 0; i < 4; i++) {
        int ra = wm * 64 + i * 16 + (lane & 15);
        a[i] = *(const bf16x8*)(As + ra * 128 + ((c16 ^ (ra & 7)) << 4));
        int rb = wn * 64 + i * 16 + (lane & 15);
        b[i] = *(const bf16x8*)(Bs + rb * 128 + ((c16 ^ (rb & 7)) << 4));
      }
#pragma unroll
      for (int i = 0; i < 4; i++)
#pragma unroll
        for (int j = 0; j < 4; j++)
          acc[i][j] = __builtin_amdgcn_mfma_f32_16x16x32_bf16(a[i], b[j], acc[i][j], 0, 0, 0);
    }
  }

  const int colbase = bn * 128 + wn * 64;
  if (bn < 32) {
    // q/k region with on-the-fly RoPE; even lanes store bf16x2 pairs.
#pragma unroll
    for (int j = 0; j < 4; j++) {
      int col = colbase + j * 16 + (lane & 15);
      int isK = col >> 11;                 // 0:q 1:k (block never straddles)
      int hh = (col >> 7) & 15, d = col & 127;
      float invr = exp2f(-0.20762050593045952f * (float)(d >> 1)) *
                   0.15915494309189535f;   // revolutions
      __bf16* dst = isK ? kr : qr;
#pragma unroll
      for (int i = 0; i < 4; i++)
#pragma unroll
        for (int r = 0; r < 4; r++) {
          int row = bm * 128 + wm * 64 + i * 16 + ((lane >> 4) << 2) + r;
          int bb = row >> 11, srel = row & 2047;
          float me = acc[i][j][r];
          float pv = __shfl_xor(me, 1);   // partner (both lanes exec)
          if (!(lane & 1)) {
            float ar = (float)srel * invr;
            ar = ar - floorf(ar);
            float cs = __builtin_amdgcn_cosf(ar);
            float sn = __builtin_amdgcn_sinf(ar);
            bf16x2 pk;
            pk[0] = (__bf16)(me * cs - pv * sn);
            pk[1] = (__bf16)(pv * cs + me * sn);
            *(bf16x2*)(dst + ((size_t)((bb * 16 + hh) * 2048 + srel)) * 128 + d) = pk;
          }
        }
    }
  } else {
    // v region -> transposed store
#pragma unroll
    for (int i = 0; i < 4; i++)
#pragma unroll
      for (int j = 0; j < 4; j++) {
        int col = colbase + j * 16 + (lane & 15) - 4096;
        int hh = col >> 7, d = col & 127;
        int row0 = bm * 128 + wm * 64 + i * 16 + ((lane >> 4) << 2);
        int bb = row0 >> 11, srel = row0 & 2047;
        bf16x4 pk;
#pragma unroll
        for (int r = 0; r < 4; r++) pk[r] = (__bf16)acc[i][j][r];
        *(bf16x4*)(vt + ((size_t)((bb * 16 + hh) * 128 + d)) * 2048 + srel) = pk;
      }
  }
}

// ---------------------------------------------------------------------------
// GEMM 256x128, BK=64, 8 waves (4M x 2N, each 64x64), 2 phases/K-tile,
// counted vmcnt(6) once per K-tile. A double-buffered (2 halves x 2 = 64KB),
// B TRIPLE-buffered (1 half x 3 = 48KB) so each B prefetch targets a dead
// slot. Grid (N/128, M/256) — for N=2048, M=4096: 16x16 = exactly 256 blocks
// = one full round. Drain proof: vmcnt(6) at ph2(t) leaves exactly
// {B(t+2), A0(t+2), A1(t+2)} in flight -> tiles <= t+1 landed before use.
// Stages: ph1(t) -> B(t+2) (overwrites B(t-1), last read ph2(t-1));
//         ph2(t) -> A(t+2) (overwrites A(t), last read ph1(t)).
// A-fragments are loaded once in ph1 and reused in ph2 (j-halves split).
// ---------------------------------------------------------------------------
template <int EPI>
__global__ __launch_bounds__(512, 2) void gemm_bt2(
    const __bf16* __restrict__ A, const __bf16* __restrict__ BT,
    void* __restrict__ Cout, const float* __restrict__ res, int M, int N, int K) {
  __shared__ char lds[114688];
  const int tid = threadIdx.x, lane = tid & 63, w = tid >> 6;
  const int wm = w >> 1, wn = w & 1;  // 4 M-waves x 2 N-waves
  const int bn = blockIdx.x, bm = blockIdx.y;

  f32x4 acc[4][4];
#pragma unroll
  for (int i = 0; i < 4; i++)
#pragma unroll
    for (int j = 0; j < 4; j++) acc[i][j] = (f32x4){0.f, 0.f, 0.f, 0.f};

  const size_t strideA = (size_t)K * 2;
  const int r0 = tid >> 3, s0 = tid & 7, r1 = r0 + 64;
  const char* Ab0 = (const char*)A + (size_t)(bm * 256) * strideA;
  const char* Bb0 = (const char*)BT + (size_t)(bn * 128) * strideA;

  auto stageA = [&](int h, int kt, int buf) {
    const char* g = Ab0 + (size_t)(h * 128) * strideA + (size_t)kt * 128;
    char* d = lds + buf * 32768 + h * 16384;
    gload16(g + (size_t)r0 * strideA + ((s0 ^ (r0 & 7)) << 4), d + tid * 16);
    gload16(g + (size_t)r1 * strideA + ((s0 ^ (r1 & 7)) << 4), d + (tid + 512) * 16);
  };
  auto stageB = [&](int kt, int slot3) {
    const char* g = Bb0 + (size_t)kt * 128;
    char* d = lds + 65536 + slot3 * 16384;
    gload16(g + (size_t)r0 * strideA + ((s0 ^ (r0 & 7)) << 4), d + tid * 16);
    gload16(g + (size_t)r1 * strideA + ((s0 ^ (r1 & 7)) << 4), d + (tid + 512) * 16);
  };
  auto ldA = [&](bf16x8 (&a)[4][2], int buf) {
    const char* base = lds + buf * 32768 + (wm >> 1) * 16384;
#pragma unroll
    for (int i = 0; i < 4; i++)
#pragma unroll
      for (int kk = 0; kk < 2; kk++) {
        int rl = (wm & 1) * 64 + i * 16 + (lane & 15);
        int c16 = kk * 4 + (lane >> 4);
        a[i][kk] = *(const bf16x8*)(base + rl * 128 + ((c16 ^ (rl & 7)) << 4));
      }
  };
  auto ldB = [&](bf16x8 (&b)[2][2], int slot3, int jb) {
    const char* base = lds + 65536 + slot3 * 16384;
#pragma unroll
    for (int j = 0; j < 2; j++)
#pragma unroll
      for (int kk = 0; kk < 2; kk++) {
        int rl = wn * 64 + jb * 32 + j * 16 + (lane & 15);
        int c16 = kk * 4 + (lane >> 4);
        b[j][kk] = *(const bf16x8*)(base + rl * 128 + ((c16 ^ (rl & 7)) << 4));
      }
  };

  const int NT = K >> 6;
  // prologue: B(0) A0(0) A1(0) | B(1) A0(1) A1(1)  (12 loads)
  stageB(0, 0); stageA(0, 0, 0); stageA(1, 0, 0);
  stageB(1, 1); stageA(0, 1, 1); stageA(1, 1, 1);
  asm volatile("s_waitcnt vmcnt(6)" ::: "memory");  // tile0 landed
  __builtin_amdgcn_s_barrier();

  bf16x8 a[4][2], b[2][2];
  for (int t = 0; t < NT; ++t) {
    const int buf = t & 1;
    const int slot = t % 3;
    const int tp = (t + 2 < NT) ? t + 2 : NT - 1;  // clamped prefetch targets
    const int slotp = (t + 2) % 3;                  // are never-read slots
    // --- ph1: A frags + B j01 ; stage B(t+2) ---
    ldA(a, buf);
    ldB(b, slot, 0);
    stageB(tp, slotp);
    __builtin_amdgcn_s_barrier();
    __builtin_amdgcn_s_setprio(1);
#pragma unroll
    for (int i = 0; i < 4; i++)
#pragma unroll
      for (int j = 0; j < 2; j++)
#pragma unroll
        for (int kk = 0; kk < 2; kk++)
          acc[i][j] = __builtin_amdgcn_mfma_f32_16x16x32_bf16(a[i][kk], b[j][kk], acc[i][j], 0, 0, 0);
    __builtin_amdgcn_s_setprio(0);
    __builtin_amdgcn_s_barrier();
    // --- ph2: B j23 ; stage A(t+2) ; counted wait ---
    ldB(b, slot, 1);
    stageA(0, tp, buf);
    stageA(1, tp, buf);
    asm volatile("s_waitcnt vmcnt(6)" ::: "memory");  // t+1 fully landed
    __builtin_amdgcn_s_barrier();
    __builtin_amdgcn_s_setprio(1);
#pragma unroll
    for (int i = 0; i < 4; i++)
#pragma unroll
      for (int j = 0; j < 2; j++)
#pragma unroll
        for (int kk = 0; kk < 2; kk++)
          acc[i][2 + j] = __builtin_amdgcn_mfma_f32_16x16x32_bf16(a[i][kk], b[j][kk], acc[i][2 + j], 0, 0, 0);
    __builtin_amdgcn_s_setprio(0);
    __builtin_amdgcn_s_barrier();
  }
  asm volatile("s_waitcnt vmcnt(0)" ::: "memory");

#pragma unroll
  for (int i = 0; i < 4; i++)
#pragma unroll
    for (int j = 0; j < 4; j++)
#pragma unroll
      for (int r = 0; r < 4; r++) {
        int row = bm * 256 + wm * 64 + i * 16 + ((lane >> 4) << 2) + r;
        int col = bn * 128 + wn * 64 + j * 16 + (lane & 15);
        size_t idx = (size_t)row * N + col;
        float v = acc[i][j][r];
        if (EPI == 0) {
          ((__bf16*)Cout)[idx] = (__bf16)v;
        } else if (EPI == 1) {
          ((float*)Cout)[idx] = v + res[idx];
        } else {
          float u = 0.7978845608028654f * (v + 0.044715f * v * v * v);
          ((__bf16*)Cout)[idx] = (__bf16)(0.5f * v * (1.0f + tanhf(u)));
        }
      }
}

// ---------------------------------------------------------------------------
// GEMM 256x256 8-phase — R4/R5 proven schedule (fc only; do not touch, see
// R7 race post-mortem).
// ---------------------------------------------------------------------------
#define MMQ(IB, JB, AR, BR)                                                   \
  __builtin_amdgcn_s_setprio(1);                                              \
  _Pragma("unroll") for (int i = 0; i < 4; i++)                               \
      _Pragma("unroll") for (int j = 0; j < 2; j++)                           \
          _Pragma("unroll") for (int kk = 0; kk < 2; kk++)                    \
              acc[(IB)*4 + i][(JB)*2 + j] =                                   \
      __builtin_amdgcn_mfma_f32_16x16x32_bf16(                                \
          AR[i][kk], BR[j][kk], acc[(IB)*4 + i][(JB)*2 + j], 0, 0, 0);        \
  __builtin_amdgcn_s_setprio(0);

template <int EPI>
__global__ __launch_bounds__(512, 2) void gemm256(
    const __bf16* __restrict__ A, const __bf16* __restrict__ BT,
    void* __restrict__ Cout, const float* __restrict__ res, int M, int N, int K) {
  __shared__ char lds[131072];
  const int tid = threadIdx.x, lane = tid & 63, w = tid >> 6;
  const int wm = w >> 2, wn = w & 3;
  const int bn = blockIdx.x, bm = blockIdx.y;

  f32x4 acc[8][4];
#pragma unroll
  for (int i = 0; i < 8; i++)
#pragma unroll
    for (int j = 0; j < 4; j++) acc[i][j] = (f32x4){0.f, 0.f, 0.f, 0.f};

  const size_t strideA = (size_t)K * 2;
  const int r0 = tid >> 3, s0 = tid & 7;
  const int r1 = r0 + 64;
  const char* Ab0 = (const char*)A + (size_t)(bm * 256) * strideA;
  const char* Bb0 = (const char*)BT + (size_t)(bn * 256) * strideA;

  auto stage = [&](int isB, int h, int kt, int buf) {
    const char* g = (isB ? Bb0 : Ab0) + (size_t)(h * 128) * strideA + (size_t)kt * 128;
    char* d = lds + isB * 65536 + buf * 32768 + h * 16384;
    gload16(g + (size_t)r0 * strideA + ((s0 ^ (r0 & 7)) << 4), d + tid * 16);
    gload16(g + (size_t)r1 * strideA + ((s0 ^ (r1 & 7)) << 4), d + (tid + 512) * 16);
  };
  auto ldA = [&](bf16x8 (&a)[4][2], int buf, int bank) {
    const char* base = lds + buf * 32768 + wm * 16384;
#pragma unroll
    for (int i = 0; i < 4; i++)
#pragma unroll
      for (int kk = 0; kk < 2; kk++) {
        int rl = bank * 64 + i * 16 + (lane & 15);
        int c16 = kk * 4 + (lane >> 4);
        a[i][kk] = *(const bf16x8*)(base + rl * 128 + ((c16 ^ (rl & 7)) << 4));
      }
  };
  auto ldB = [&](bf16x8 (&b)[2][2], int buf, int jb) {
    const char* base = lds + 65536 + buf * 32768 + (wn >> 1) * 16384;
#pragma unroll
    for (int j = 0; j < 2; j++)
#pragma unroll
      for (int kk = 0; kk < 2; kk++) {
        int rl = (wn & 1) * 64 + jb * 32 + j * 16 + (lane & 15);
        int c16 = kk * 4 + (lane >> 4);
        b[j][kk] = *(const bf16x8*)(base + rl * 128 + ((c16 ^ (rl & 7)) << 4));
      }
  };

  const int NT = K >> 6;
  stage(1, 0, 0, 0); stage(1, 1, 0, 0); stage(0, 0, 0, 0); stage(0, 1, 0, 0);
  stage(1, 0, 1, 1); stage(1, 1, 1, 1); stage(0, 0, 1, 1); stage(0, 1, 1, 1);
  asm volatile("s_waitcnt vmcnt(6)" ::: "memory");
  __builtin_amdgcn_s_barrier();

  bf16x8 a[4][2], b0[2][2], b1[2][2];
  for (int it = 0; it < (NT >> 1); ++it) {
    const int e = 2 * it;
    const int ep = (e + 2 < NT) ? e + 2 : NT - 1;
    const int op = (e + 3 < NT) ? e + 3 : NT - 1;
    // ph1
    ldA(a, 0, 0); ldB(b0, 0, 0);
    __builtin_amdgcn_s_barrier();
    MMQ(0, 0, a, b0);
    __builtin_amdgcn_s_barrier();
    // ph2
    ldB(b1, 0, 1);
    __builtin_amdgcn_s_barrier();
    MMQ(0, 1, a, b1);
    __builtin_amdgcn_s_barrier();
    // ph3
    ldA(a, 0, 1); stage(1, 0, ep, 0);
    __builtin_amdgcn_s_barrier();
    MMQ(1, 1, a, b1);
    __builtin_amdgcn_s_barrier();
    // ph4
    stage(1, 1, ep, 0);
    asm volatile("s_waitcnt vmcnt(4)" ::: "memory");
    __builtin_amdgcn_s_barrier();
    MMQ(1, 0, a, b0);
    __builtin_amdgcn_s_barrier();
    // ph5
    ldA(a, 1, 0); ldB(b0, 1, 0); stage(0, 0, ep, 0);
    __builtin_amdgcn_s_barrier();
    MMQ(0, 0, a, b0);
    __builtin_amdgcn_s_barrier();
    // ph6
    ldB(b1, 1, 1); stage(0, 1, ep, 0);
    __builtin_amdgcn_s_barrier();
    MMQ(0, 1, a, b1);
    __builtin_amdgcn_s_barrier();
    // ph7
    ldA(a, 1, 1); stage(1, 0, op, 1);
    __builtin_amdgcn_s_barrier();
    MMQ(1, 1, a, b1);
    __builtin_amdgcn_s_barrier();
    // ph8
    stage(1, 1, op, 1); stage(0, 0, op, 1); stage(0, 1, op, 1);
    asm volatile("s_waitcnt vmcnt(6)" ::: "memory");
    __builtin_amdgcn_s_barrier();
    MMQ(1, 0, a, b0);
    __builtin_amdgcn_s_barrier();
  }
  asm volatile("s_waitcnt vmcnt(0)" ::: "memory");

#pragma unroll
  for (int i = 0; i < 8; i++)
#pragma unroll
    for (int j = 0; j < 4; j++)
#pragma unroll
      for (int r = 0; r < 4; r++) {
        int row = bm * 256 + wm * 128 + i * 16 + ((lane >> 4) << 2) + r;
        int col = bn * 256 + wn * 64 + j * 16 + (lane & 15);
        size_t idx = (size_t)row * N + col;
        float v = acc[i][j][r];
        if (EPI == 0) {
          ((__bf16*)Cout)[idx] = (__bf16)v;
        } else if (EPI == 1) {
          ((float*)Cout)[idx] = v + res[idx];
        } else {
          float u = 0.7978845608028654f * (v + 0.044715f * v * v * v);
          ((__bf16*)Cout)[idx] = (__bf16)(0.5f * v * (1.0f + tanhf(u)));
        }
      }
}

// ---------------------------------------------------------------------------
// Flash attention v2 (causal). QBLK=128 (8 waves x 16 q-rows), KVBLK=64.
// R10-proven version (LDS 80KB, 2KB P buffer/wave, no min-waves bound).
// ---------------------------------------------------------------------------
__global__ __launch_bounds__(512) void flash_attn(
    const __bf16* __restrict__ qg, const __bf16* __restrict__ kg,
    const __bf16* __restrict__ vtg, __bf16* __restrict__ og) {
  __shared__ char lds[81920];
  const int tid = threadIdx.x, lane = tid & 63, w = tid >> 6;  // w 0..7
  const int h = blockIdx.y, b = blockIdx.z;
  const int bh = b * 16 + h;
  const __bf16* qb = qg + (size_t)bh * 2048 * 128;
  const char* kbb = (const char*)(kg + (size_t)bh * 2048 * 128);
  const char* vbb = (const char*)(vtg + (size_t)bh * 128 * 2048);
  char* Pw = lds + 65536 + w * 2048;

  const char* gK[2];
  const char* gV[2];
#pragma unroll
  for (int t = 0; t < 2; t++) {
    int gg = t * 512 + tid;           // 0..1023
    int rk = gg >> 4, sk = gg & 15;   // K row 0..63, slot 0..15
    gK[t] = kbb + rk * 256 + ((sk ^ (rk & 15)) << 4);
    int rv = gg >> 3, sv = gg & 7;    // V row 0..127, slot 0..7
    gV[t] = vbb + rv * 4096 + ((sv ^ (rv & 7)) << 4);
  }

  const float SL2E = 0.08838834764831845f * 1.4426950408889634f;  // scale*log2(e)

  auto stageKV = [&](int kt, int buf) {
#pragma unroll
    for (int t = 0; t < 2; t++) {
      int gg = t * 512 + tid;
      gload16(gK[t] + (size_t)kt * 16384, lds + buf * 16384 + gg * 16);
      gload16(gV[t] + (size_t)kt * 128, lds + 32768 + buf * 16384 + gg * 16);
    }
  };

  auto run_qtile = [&](int qt) {
    const int qrow0 = qt * 128 + w * 16;
    bf16x8 qf[4];
#pragma unroll
    for (int c = 0; c < 4; c++) {
      bf16x8 raw = *(const bf16x8*)(qb + (size_t)(qrow0 + (lane & 15)) * 128 +
                                    c * 32 + ((lane >> 4) << 3));
#pragma unroll
      for (int e = 0; e < 8; e++) qf[c][e] = (__bf16)((float)raw[e] * SL2E);
    }
    float m[4], lsp[4];
    f32x4 o[8];
#pragma unroll
    for (int r = 0; r < 4; r++) { m[r] = -__builtin_inff(); lsp[r] = 0.f; }
#pragma unroll
    for (int n = 0; n < 8; n++) o[n] = (f32x4){0.f, 0.f, 0.f, 0.f};

    const int NKT = 2 * qt + 2;
    stageKV(0, 0);

    for (int kt = 0; kt < NKT; kt++) {
      const int cur = kt & 1;
      const char* Ks = lds + cur * 16384;
      const char* Vs = lds + 32768 + cur * 16384;
      if (kt < NKT - 1) {
        stageKV(kt + 1, cur ^ 1);
        asm volatile("s_waitcnt vmcnt(4)" ::: "memory");  // current tile landed
      } else {
        asm volatile("s_waitcnt vmcnt(0)" ::: "memory");
      }
      __builtin_amdgcn_s_barrier();

      f32x4 s[4];
      __builtin_amdgcn_s_setprio(1);
#pragma unroll
      for (int n = 0; n < 4; n++) {
        s[n] = (f32x4){0.f, 0.f, 0.f, 0.f};
#pragma unroll
        for (int c = 0; c < 4; c++) {
          int krow = n * 16 + (lane & 15);
          int c16 = c * 4 + (lane >> 4);
          bf16x8 kf = *(const bf16x8*)(Ks + krow * 256 + ((c16 ^ (krow & 15)) << 4));
          s[n] = __builtin_amdgcn_mfma_f32_16x16x32_bf16(qf[c], kf, s[n], 0, 0, 0);
        }
      }
      __builtin_amdgcn_s_setprio(0);

      if (kt * 64 + 63 > qrow0) {
#pragma unroll
        for (int r = 0; r < 4; r++) {
          const int qrow = qrow0 + ((lane >> 4) << 2) + r;
#pragma unroll
          for (int n = 0; n < 4; n++) {
            int col = kt * 64 + n * 16 + (lane & 15);
            if (col > qrow) s[n][r] = -__builtin_inff();
          }
        }
      }

      float tmx[4];
#pragma unroll
      for (int r = 0; r < 4; r++)
        tmx[r] = fmaxf(fmaxf(s[0][r], s[1][r]), fmaxf(s[2][r], s[3][r]));
      bool hot = (tmx[0] > m[0] + 8.f) | (tmx[1] > m[1] + 8.f) |
                 (tmx[2] > m[2] + 8.f) | (tmx[3] > m[3] + 8.f);
      if (__any(hot)) {
        float fc[4];
#pragma unroll
        for (int r = 0; r < 4; r++) {
          float gmx = tmx[r];
#pragma unroll
          for (int mk = 1; mk < 16; mk <<= 1) gmx = fmaxf(gmx, __shfl_xor(gmx, mk));
          float nm = fmaxf(m[r], gmx);
          fc[r] = __builtin_amdgcn_exp2f(m[r] - nm);
          m[r] = nm;
          lsp[r] *= fc[r];
        }
#pragma unroll
        for (int n = 0; n < 8; n++) {
          o[n][0] *= fc[0]; o[n][1] *= fc[1]; o[n][2] *= fc[2]; o[n][3] *= fc[3];
        }
      }

      float p[4][4];
#pragma unroll
      for (int r = 0; r < 4; r++) {
        float sum = 0.f;
#pragma unroll
        for (int n = 0; n < 4; n++) {
          float pv = __builtin_amdgcn_exp2f(s[n][r] - m[r]);
          p[n][r] = pv;
          sum += pv;
        }
        lsp[r] += sum;
      }

#pragma unroll
      for (int n = 0; n < 4; n++)
#pragma unroll
        for (int r = 0; r < 4; r++) {
          int prow = ((lane >> 4) << 2) + r;
          int col = n * 16 + (lane & 15);
          int ch = col >> 3;
          *(__bf16*)(Pw + prow * 128 + ((ch ^ (prow & 7)) << 4) + ((col & 7) << 1)) =
              (__bf16)p[n][r];
        }

      __builtin_amdgcn_s_setprio(1);
#pragma unroll
      for (int kk = 0; kk < 2; kk++) {
        int prow = lane & 15;
        int pc = kk * 4 + (lane >> 4);
        bf16x8 pf = *(const bf16x8*)(Pw + prow * 128 + ((pc ^ (prow & 7)) << 4));
#pragma unroll
        for (int n = 0; n < 8; n++) {
          int vr = n * 16 + (lane & 15);
          bf16x8 vf = *(const bf16x8*)(Vs + vr * 128 + ((pc ^ (vr & 7)) << 4));
          o[n] = __builtin_amdgcn_mfma_f32_16x16x32_bf16(pf, vf, o[n], 0, 0, 0);
        }
      }
      __builtin_amdgcn_s_setprio(0);
      __builtin_amdgcn_s_barrier();
    }

    float inv[4];
#pragma unroll
    for (int r = 0; r < 4; r++) {
      float ls = lsp[r];
#pragma unroll
      for (int mk = 1; mk < 16; mk <<= 1) ls += __shfl_xor(ls, mk);
      inv[r] = 1.0f / ls;
    }
#pragma unroll
    for (int n = 0; n < 8; n++)
#pragma unroll
      for (int r = 0; r < 4; r++) {
        int qrow = qrow0 + ((lane >> 4) << 2) + r;
        og[(size_t)(b * 2048 + qrow) * 2048 + h * 128 + n * 16 + (lane & 15)] =
            (__bf16)(o[n][r] * inv[r]);
      }
  };

  run_qtile(15 - (int)blockIdx.x);
  run_qtile((int)blockIdx.x);
}

// ---------------------------------------------------------------------------
extern "C" void kernel_launch(void* const* d_in, const int* in_sizes, int n_in,
                              void* d_out, int out_size, void* d_ws, size_t ws_size,
                              hipStream_t stream) {
  const float* x = (const float*)d_in[0];
  const float* w_qkv = (const float*)d_in[1];
  const float* w_out = (const float*)d_in[2];
  const float* w_fc = (const float*)d_in[3];
  const float* w_proj = (const float*)d_in[4];
  const float* g_in = (const float*)d_in[5];
  const float* g_ff = (const float*)d_in[6];
  float* out = (float*)d_out;
  char* ws = (char*)d_ws;

  constexpr size_t O_WQKV = 0;           // bf16 [6144][2048]
  constexpr size_t O_WOUT = 25165824;    // bf16 [2048][2048]
  constexpr size_t O_WFC = 33554432;     // bf16 [4096][2048]
  constexpr size_t O_WPROJ = 50331648;   // bf16 [2048][4096]
  constexpr size_t O_H = 67108864;       // bf16 [4096][2048]
  constexpr size_t O_QKV = 83886080;     // bf16 fcact [4096][4096]
  constexpr size_t O_Q = 134217728;      // bf16 [2][16][2048][128]
  constexpr size_t O_K = 150994944;
  constexpr size_t O_VT = 167772160;     // bf16 [2][16][128][2048]
  constexpr size_t O_ATTN = 185597952;   // bf16 [4096][2048]
  constexpr size_t O_X1 = 202375168;     // f32 [4096][2048]

  __bf16* wqkvT = (__bf16*)(ws + O_WQKV);
  __bf16* woutT = (__bf16*)(ws + O_WOUT);
  __bf16* wfcT = (__bf16*)(ws + O_WFC);
  __bf16* wprojT = (__bf16*)(ws + O_WPROJ);
  __bf16* h = (__bf16*)(ws + O_H);
  __bf16* fcact = (__bf16*)(ws + O_QKV);
  __bf16* qr = (__bf16*)(ws + O_Q);
  __bf16* kr = (__bf16*)(ws + O_K);
  __bf16* vt = (__bf16*)(ws + O_VT);
  __bf16* attn = (__bf16*)(ws + O_ATTN);
  float* x1 = (float*)(ws + O_X1);

  // all four weight transposes in one launch
  transpose_cvt_all<<<8192, 256, 0, stream>>>(w_qkv, w_out, w_fc, w_proj,
                                              wqkvT, woutT, wfcT, wprojT);
  // h = rmsnorm(x, g_in)
  rmsnorm_kernel<<<4096, 256, 0, stream>>>(x, g_in, h);
  // q,k (roped, on-the-fly sin/cos) + v^T from the qkv GEMM epilogue
  gemm_qkv<<<dim3(48, 32), 256, 0, stream>>>(h, wqkvT, qr, kr, vt, 2048);
  // attention (QBLK=128, balanced pairs)
  flash_attn<<<dim3(8, 16, 2), 512, 0, stream>>>(qr, kr, vt, attn);
  // x1 = x + attn @ w_out   (256x128 tiles, exactly 256 blocks)
  gemm_bt2<1><<<dim3(16, 16), 512, 0, stream>>>(attn, woutT, (void*)x1, x, 4096, 2048, 2048);
  // h2 = rmsnorm(x1, g_ff)
  rmsnorm_kernel<<<4096, 256, 0, stream>>>(x1, g_ff, h);
  // fcact = gelu(h2 @ w_fc)  (256^2 8-phase, grid 16x16 = exactly 1 round)
  gemm256<2><<<dim3(16, 16), 512, 0, stream>>>(h, wfcT, (void*)fcact, nullptr, 4096, 4096, 2048);
  // out = x1 + fcact @ w_proj  (256x128 tiles, exactly 256 blocks)
  gemm_bt2<1><<<dim3(16, 16), 512, 0, stream>>>(fcact, wprojT, (void*)out, x1, 4096, 2048, 4096);
}

// Round 15
// 447.826 us; speedup vs baseline: 1.0373x; 1.0373x over previous
//
#include <hip/hip_runtime.h>
#include <math.h>

typedef __bf16 bf16x8 __attribute__((ext_vector_type(8)));
typedef __bf16 bf16x4 __attribute__((ext_vector_type(4)));
typedef __bf16 bf16x2 __attribute__((ext_vector_type(2)));
typedef float  f32x4  __attribute__((ext_vector_type(4)));

#define DEV __device__ __forceinline__

DEV void gload16(const void* g, void* l) {
  __builtin_amdgcn_global_load_lds(
      (const __attribute__((address_space(1))) void*)g,
      (__attribute__((address_space(3))) void*)l, 16, 0, 0);
}

// ---------------------------------------------------------------------------
// All four weight transposes in ONE launch. f32 [R][C] -> bf16 [C][R],
// 64x64 tiles, float4 reads / bf16x8 writes. Flat grid 8192 blocks.
// ---------------------------------------------------------------------------
__global__ __launch_bounds__(256) void transpose_cvt_all(
    const float* __restrict__ w_qkv, const float* __restrict__ w_out,
    const float* __restrict__ w_fc, const float* __restrict__ w_proj,
    __bf16* __restrict__ o_qkv, __bf16* __restrict__ o_out,
    __bf16* __restrict__ o_fc, __bf16* __restrict__ o_proj) {
  const int bid = blockIdx.x;
  const float* in;
  __bf16* outT;
  int R, C, bx, by;
  if (bid < 3072) {
    in = w_qkv; outT = o_qkv; R = 2048; C = 6144;
    bx = bid % 96; by = bid / 96;
  } else if (bid < 4096) {
    in = w_out; outT = o_out; R = 2048; C = 2048;
    int l = bid - 3072; bx = l & 31; by = l >> 5;
  } else if (bid < 6144) {
    in = w_fc; outT = o_fc; R = 2048; C = 4096;
    int l = bid - 4096; bx = l & 63; by = l >> 6;
  } else {
    in = w_proj; outT = o_proj; R = 4096; C = 2048;
    int l = bid - 6144; bx = l & 31; by = l >> 5;
  }
  __shared__ float t[64][65];
  const int c0 = bx * 64, r0 = by * 64;
  const int tid = threadIdx.x;
#pragma unroll
  for (int i = 0; i < 4; i++) {
    int r = (tid >> 4) + i * 16;
    int cf = tid & 15;
    float4 v = *(const float4*)(in + (size_t)(r0 + r) * C + c0 + cf * 4);
    t[r][cf * 4 + 0] = v.x; t[r][cf * 4 + 1] = v.y;
    t[r][cf * 4 + 2] = v.z; t[r][cf * 4 + 3] = v.w;
  }
  __syncthreads();
#pragma unroll
  for (int i = 0; i < 2; i++) {
    int c = (tid >> 3) + i * 32;
    int r8 = tid & 7;
    bf16x8 ov;
#pragma unroll
    for (int k = 0; k < 8; k++) ov[k] = (__bf16)t[r8 * 8 + k][c];
    *(bf16x8*)(outT + (size_t)(c0 + c) * R + r0 + r8 * 8) = ov;
  }
}

// ---------------------------------------------------------------------------
// RMSNorm row kernel: f32 [rows][2048] -> bf16, 1 block/row, 8 elems/thread.
// ---------------------------------------------------------------------------
__global__ __launch_bounds__(256) void rmsnorm_kernel(
    const float* __restrict__ x, const float* __restrict__ g, __bf16* __restrict__ out) {
  const int r = blockIdx.x, t = threadIdx.x;
  const float4* xr = (const float4*)(x + (size_t)r * 2048);
  float4 a = xr[2 * t], b = xr[2 * t + 1];
  float ss = a.x * a.x + a.y * a.y + a.z * a.z + a.w * a.w +
             b.x * b.x + b.y * b.y + b.z * b.z + b.w * b.w;
#pragma unroll
  for (int mk = 1; mk < 64; mk <<= 1) ss += __shfl_xor(ss, mk);
  __shared__ float red[4];
  if ((t & 63) == 0) red[t >> 6] = ss;
  __syncthreads();
  const float sc = rsqrtf((red[0] + red[1] + red[2] + red[3]) * (1.0f / 2048.0f) + 1e-6f);
  const float4* gr = (const float4*)g;
  float4 ga = gr[2 * t], gb = gr[2 * t + 1];
  bf16x8 ov;
  ov[0] = (__bf16)(a.x * sc * ga.x); ov[1] = (__bf16)(a.y * sc * ga.y);
  ov[2] = (__bf16)(a.z * sc * ga.z); ov[3] = (__bf16)(a.w * sc * ga.w);
  ov[4] = (__bf16)(b.x * sc * gb.x); ov[5] = (__bf16)(b.y * sc * gb.y);
  ov[6] = (__bf16)(b.z * sc * gb.z); ov[7] = (__bf16)(b.w * sc * gb.w);
  *(bf16x8*)(out + (size_t)r * 2048 + t * 8) = ov;
}

// ---------------------------------------------------------------------------
// GEMM 128x128 (m97 structure, 895 TF) — wout / proj.
// EPI: 0 = bf16 store, 1 = f32 store + residual, 2 = gelu -> bf16.
// ---------------------------------------------------------------------------
template <int EPI>
__global__ __launch_bounds__(256) void gemm_bt(
    const __bf16* __restrict__ A, const __bf16* __restrict__ BT,
    void* __restrict__ Cout, const float* __restrict__ res, int M, int N, int K) {
  __shared__ char lds[32768];
  char* As = lds;
  char* Bs = lds + 16384;
  const int tid = threadIdx.x;
  const int lane = tid & 63;
  const int bn = blockIdx.x, bm = blockIdx.y;
  const int wm = tid >> 7, wn = (tid >> 6) & 1;

  f32x4 acc[4][4];
#pragma unroll
  for (int i = 0; i < 4; i++)
#pragma unroll
    for (int j = 0; j < 4; j++) acc[i][j] = (f32x4){0.f, 0.f, 0.f, 0.f};

  const size_t strideA = (size_t)K * 2;
  const char* ga[4];
  const char* gb[4];
#pragma unroll
  for (int t = 0; t < 4; t++) {
    int gg = t * 256 + tid;
    int row = gg >> 3, slot = gg & 7;
    ga[t] = (const char*)A + (size_t)(bm * 128 + row) * strideA + ((slot ^ (row & 7)) << 4);
    gb[t] = (const char*)BT + (size_t)(bn * 128 + row) * strideA + ((slot ^ (row & 7)) << 4);
  }

  for (int k0 = 0; k0 < K; k0 += 64) {
    __syncthreads();
#pragma unroll
    for (int t = 0; t < 4; t++) {
      int gg = t * 256 + tid;
      gload16(ga[t], As + gg * 16);
      gload16(gb[t], Bs + gg * 16);
      ga[t] += 128;
      gb[t] += 128;
    }
    __syncthreads();
#pragma unroll
    for (int kk = 0; kk < 2; kk++) {
      bf16x8 a[4], b[4];
      const int c16 = kk * 4 + (lane >> 4);
#pragma unroll
      for (int i = 0; i < 4; i++) {
        int ra = wm * 64 + i * 16 + (lane & 15);
        a[i] = *(const bf16x8*)(As + ra * 128 + ((c16 ^ (ra & 7)) << 4));
        int rb = wn * 64 + i * 16 + (lane & 15);
        b[i] = *(const bf16x8*)(Bs + rb * 128 + ((c16 ^ (rb & 7)) << 4));
      }
#pragma unroll
      for (int i = 0; i < 4; i++)
#pragma unroll
        for (int j = 0; j < 4; j++)
          acc[i][j] = __builtin_amdgcn_mfma_f32_16x16x32_bf16(a[i], b[j], acc[i][j], 0, 0, 0);
    }
  }

#pragma unroll
  for (int i = 0; i < 4; i++)
#pragma unroll
    for (int j = 0; j < 4; j++)
#pragma unroll
      for (int r = 0; r < 4; r++) {
        int row = bm * 128 + wm * 64 + i * 16 + ((lane >> 4) << 2) + r;
        int col = bn * 128 + wn * 64 + j * 16 + (lane & 15);
        size_t idx = (size_t)row * N + col;
        float v = acc[i][j][r];
        if (EPI == 0) {
          ((__bf16*)Cout)[idx] = (__bf16)v;
        } else if (EPI == 1) {
          ((float*)Cout)[idx] = v + res[idx];
        } else {
          float u = 0.7978845608028654f * (v + 0.044715f * v * v * v);
          ((__bf16*)Cout)[idx] = (__bf16)(0.5f * v * (1.0f + tanhf(u)));
        }
      }
}

// ---------------------------------------------------------------------------
// QKV GEMM with fused RoPE + head-split + V-transpose epilogue.
// R10 proven version: direct stores, on-the-fly cos/sin (revolutions domain),
// pair-store bf16x2 on even lanes.
// ---------------------------------------------------------------------------
__global__ __launch_bounds__(256, 6) void gemm_qkv(
    const __bf16* __restrict__ A, const __bf16* __restrict__ BT,
    __bf16* __restrict__ qr, __bf16* __restrict__ kr, __bf16* __restrict__ vt,
    int K) {
  __shared__ char lds[32768];
  char* As = lds;
  char* Bs = lds + 16384;
  const int tid = threadIdx.x;
  const int lane = tid & 63;
  const int bn = blockIdx.x, bm = blockIdx.y;
  const int wm = tid >> 7, wn = (tid >> 6) & 1;

  f32x4 acc[4][4];
#pragma unroll
  for (int i = 0; i < 4; i++)
#pragma unroll
    for (int j = 0; j < 4; j++) acc[i][j] = (f32x4){0.f, 0.f, 0.f, 0.f};

  const size_t strideA = (size_t)K * 2;
  const char* ga[4];
  const char* gb[4];
#pragma unroll
  for (int t = 0; t < 4; t++) {
    int gg = t * 256 + tid;
    int row = gg >> 3, slot = gg & 7;
    ga[t] = (const char*)A + (size_t)(bm * 128 + row) * strideA + ((slot ^ (row & 7)) << 4);
    gb[t] = (const char*)BT + (size_t)(bn * 128 + row) * strideA + ((slot ^ (row & 7)) << 4);
  }

  for (int k0 = 0; k0 < K; k0 += 64) {
    __syncthreads();
#pragma unroll
    for (int t = 0; t < 4; t++) {
      int gg = t * 256 + tid;
      gload16(ga[t], As + gg * 16);
      gload16(gb[t], Bs + gg * 16);
      ga[t] += 128;
      gb[t] += 128;
    }
    __syncthreads();
#pragma unroll
    for (int kk = 0; kk < 2; kk++) {
      bf16x8 a[4], b[4];
      const int c16 = kk * 4 + (lane >> 4);
#pragma unroll
      for (int i = 0; i < 4; i++) {
        int ra = wm * 64 + i * 16 + (lane & 15);
        a[i] = *(const bf16x8*)(As + ra * 128 + ((c16 ^ (ra & 7)) << 4));
        int rb = wn * 64 + i * 16 + (lane & 15);
        b[i] = *(const bf16x8*)(Bs + rb * 128 + ((c16 ^ (rb & 7)) << 4));
      }
#pragma unroll
      for (int i = 0; i < 4; i++)
#pragma unroll
        for (int j = 0; j < 4; j++)
          acc[i][j] = __builtin_amdgcn_mfma_f32_16x16x32_bf16(a[i], b[j], acc[i][j], 0, 0, 0);
    }
  }

  const int colbase = bn * 128 + wn * 64;
  if (bn < 32) {
    // q/k region with on-the-fly RoPE; even lanes store bf16x2 pairs.
#pragma unroll
    for (int j = 0; j < 4; j++) {
      int col = colbase + j * 16 + (lane & 15);
      int isK = col >> 11;                 // 0:q 1:k (block never straddles)
      int hh = (col >> 7) & 15, d = col & 127;
      float invr = exp2f(-0.20762050593045952f * (float)(d >> 1)) *
                   0.15915494309189535f;   // revolutions
      __bf16* dst = isK ? kr : qr;
#pragma unroll
      for (int i = 0; i < 4; i++)
#pragma unroll
        for (int r = 0; r < 4; r++) {
          int row = bm * 128 + wm * 64 + i * 16 + ((lane >> 4) << 2) + r;
          int bb = row >> 11, srel = row & 2047;
          float me = acc[i][j][r];
          float pv = __shfl_xor(me, 1);   // partner (both lanes exec)
          if (!(lane & 1)) {
            float ar = (float)srel * invr;
            ar = ar - floorf(ar);
            float cs = __builtin_amdgcn_cosf(ar);
            float sn = __builtin_amdgcn_sinf(ar);
            bf16x2 pk;
            pk[0] = (__bf16)(me * cs - pv * sn);
            pk[1] = (__bf16)(pv * cs + me * sn);
            *(bf16x2*)(dst + ((size_t)((bb * 16 + hh) * 2048 + srel)) * 128 + d) = pk;
          }
        }
    }
  } else {
    // v region -> transposed store
#pragma unroll
    for (int i = 0; i < 4; i++)
#pragma unroll
      for (int j = 0; j < 4; j++) {
        int col = colbase + j * 16 + (lane & 15) - 4096;
        int hh = col >> 7, d = col & 127;
        int row0 = bm * 128 + wm * 64 + i * 16 + ((lane >> 4) << 2);
        int bb = row0 >> 11, srel = row0 & 2047;
        bf16x4 pk;
#pragma unroll
        for (int r = 0; r < 4; r++) pk[r] = (__bf16)acc[i][j][r];
        *(bf16x4*)(vt + ((size_t)((bb * 16 + hh) * 128 + d)) * 2048 + srel) = pk;
      }
  }
}

// ---------------------------------------------------------------------------
// GEMM 256x256 8-phase — R4/R5 proven schedule (fc only; do not touch, see
// R7 race post-mortem).
// ---------------------------------------------------------------------------
#define MMQ(IB, JB, AR, BR)                                                   \
  __builtin_amdgcn_s_setprio(1);                                              \
  _Pragma("unroll") for (int i = 0; i < 4; i++)                               \
      _Pragma("unroll") for (int j = 0; j < 2; j++)                           \
          _Pragma("unroll") for (int kk = 0; kk < 2; kk++)                    \
              acc[(IB)*4 + i][(JB)*2 + j] =                                   \
      __builtin_amdgcn_mfma_f32_16x16x32_bf16(                                \
          AR[i][kk], BR[j][kk], acc[(IB)*4 + i][(JB)*2 + j], 0, 0, 0);        \
  __builtin_amdgcn_s_setprio(0);

template <int EPI>
__global__ __launch_bounds__(512, 2) void gemm256(
    const __bf16* __restrict__ A, const __bf16* __restrict__ BT,
    void* __restrict__ Cout, const float* __restrict__ res, int M, int N, int K) {
  __shared__ char lds[131072];
  const int tid = threadIdx.x, lane = tid & 63, w = tid >> 6;
  const int wm = w >> 2, wn = w & 3;
  const int bn = blockIdx.x, bm = blockIdx.y;

  f32x4 acc[8][4];
#pragma unroll
  for (int i = 0; i < 8; i++)
#pragma unroll
    for (int j = 0; j < 4; j++) acc[i][j] = (f32x4){0.f, 0.f, 0.f, 0.f};

  const size_t strideA = (size_t)K * 2;
  const int r0 = tid >> 3, s0 = tid & 7;
  const int r1 = r0 + 64;
  const char* Ab0 = (const char*)A + (size_t)(bm * 256) * strideA;
  const char* Bb0 = (const char*)BT + (size_t)(bn * 256) * strideA;

  auto stage = [&](int isB, int h, int kt, int buf) {
    const char* g = (isB ? Bb0 : Ab0) + (size_t)(h * 128) * strideA + (size_t)kt * 128;
    char* d = lds + isB * 65536 + buf * 32768 + h * 16384;
    gload16(g + (size_t)r0 * strideA + ((s0 ^ (r0 & 7)) << 4), d + tid * 16);
    gload16(g + (size_t)r1 * strideA + ((s0 ^ (r1 & 7)) << 4), d + (tid + 512) * 16);
  };
  auto ldA = [&](bf16x8 (&a)[4][2], int buf, int bank) {
    const char* base = lds + buf * 32768 + wm * 16384;
#pragma unroll
    for (int i = 0; i < 4; i++)
#pragma unroll
      for (int kk = 0; kk < 2; kk++) {
        int rl = bank * 64 + i * 16 + (lane & 15);
        int c16 = kk * 4 + (lane >> 4);
        a[i][kk] = *(const bf16x8*)(base + rl * 128 + ((c16 ^ (rl & 7)) << 4));
      }
  };
  auto ldB = [&](bf16x8 (&b)[2][2], int buf, int jb) {
    const char* base = lds + 65536 + buf * 32768 + (wn >> 1) * 16384;
#pragma unroll
    for (int j = 0; j < 2; j++)
#pragma unroll
      for (int kk = 0; kk < 2; kk++) {
        int rl = (wn & 1) * 64 + jb * 32 + j * 16 + (lane & 15);
        int c16 = kk * 4 + (lane >> 4);
        b[j][kk] = *(const bf16x8*)(base + rl * 128 + ((c16 ^ (rl & 7)) << 4));
      }
  };

  const int NT = K >> 6;
  stage(1, 0, 0, 0); stage(1, 1, 0, 0); stage(0, 0, 0, 0); stage(0, 1, 0, 0);
  stage(1, 0, 1, 1); stage(1, 1, 1, 1); stage(0, 0, 1, 1); stage(0, 1, 1, 1);
  asm volatile("s_waitcnt vmcnt(6)" ::: "memory");
  __builtin_amdgcn_s_barrier();

  bf16x8 a[4][2], b0[2][2], b1[2][2];
  for (int it = 0; it < (NT >> 1); ++it) {
    const int e = 2 * it;
    const int ep = (e + 2 < NT) ? e + 2 : NT - 1;
    const int op = (e + 3 < NT) ? e + 3 : NT - 1;
    // ph1
    ldA(a, 0, 0); ldB(b0, 0, 0);
    __builtin_amdgcn_s_barrier();
    MMQ(0, 0, a, b0);
    __builtin_amdgcn_s_barrier();
    // ph2
    ldB(b1, 0, 1);
    __builtin_amdgcn_s_barrier();
    MMQ(0, 1, a, b1);
    __builtin_amdgcn_s_barrier();
    // ph3
    ldA(a, 0, 1); stage(1, 0, ep, 0);
    __builtin_amdgcn_s_barrier();
    MMQ(1, 1, a, b1);
    __builtin_amdgcn_s_barrier();
    // ph4
    stage(1, 1, ep, 0);
    asm volatile("s_waitcnt vmcnt(4)" ::: "memory");
    __builtin_amdgcn_s_barrier();
    MMQ(1, 0, a, b0);
    __builtin_amdgcn_s_barrier();
    // ph5
    ldA(a, 1, 0); ldB(b0, 1, 0); stage(0, 0, ep, 0);
    __builtin_amdgcn_s_barrier();
    MMQ(0, 0, a, b0);
    __builtin_amdgcn_s_barrier();
    // ph6
    ldB(b1, 1, 1); stage(0, 1, ep, 0);
    __builtin_amdgcn_s_barrier();
    MMQ(0, 1, a, b1);
    __builtin_amdgcn_s_barrier();
    // ph7
    ldA(a, 1, 1); stage(1, 0, op, 1);
    __builtin_amdgcn_s_barrier();
    MMQ(1, 1, a, b1);
    __builtin_amdgcn_s_barrier();
    // ph8
    stage(1, 1, op, 1); stage(0, 0, op, 1); stage(0, 1, op, 1);
    asm volatile("s_waitcnt vmcnt(6)" ::: "memory");
    __builtin_amdgcn_s_barrier();
    MMQ(1, 0, a, b0);
    __builtin_amdgcn_s_barrier();
  }
  asm volatile("s_waitcnt vmcnt(0)" ::: "memory");

#pragma unroll
  for (int i = 0; i < 8; i++)
#pragma unroll
    for (int j = 0; j < 4; j++)
#pragma unroll
      for (int r = 0; r < 4; r++) {
        int row = bm * 256 + wm * 128 + i * 16 + ((lane >> 4) << 2) + r;
        int col = bn * 256 + wn * 64 + j * 16 + (lane & 15);
        size_t idx = (size_t)row * N + col;
        float v = acc[i][j][r];
        if (EPI == 0) {
          ((__bf16*)Cout)[idx] = (__bf16)v;
        } else if (EPI == 1) {
          ((float*)Cout)[idx] = v + res[idx];
        } else {
          float u = 0.7978845608028654f * (v + 0.044715f * v * v * v);
          ((__bf16*)Cout)[idx] = (__bf16)(0.5f * v * (1.0f + tanhf(u)));
        }
      }
}

// ---------------------------------------------------------------------------
// Flash attention v2 (causal). QBLK=128 (8 waves x 16 q-rows), KVBLK=64.
// R10-proven version (LDS 80KB, 2KB P buffer/wave, no min-waves bound).
// ---------------------------------------------------------------------------
__global__ __launch_bounds__(512) void flash_attn(
    const __bf16* __restrict__ qg, const __bf16* __restrict__ kg,
    const __bf16* __restrict__ vtg, __bf16* __restrict__ og) {
  __shared__ char lds[81920];
  const int tid = threadIdx.x, lane = tid & 63, w = tid >> 6;  // w 0..7
  const int h = blockIdx.y, b = blockIdx.z;
  const int bh = b * 16 + h;
  const __bf16* qb = qg + (size_t)bh * 2048 * 128;
  const char* kbb = (const char*)(kg + (size_t)bh * 2048 * 128);
  const char* vbb = (const char*)(vtg + (size_t)bh * 128 * 2048);
  char* Pw = lds + 65536 + w * 2048;

  const char* gK[2];
  const char* gV[2];
#pragma unroll
  for (int t = 0; t < 2; t++) {
    int gg = t * 512 + tid;           // 0..1023
    int rk = gg >> 4, sk = gg & 15;   // K row 0..63, slot 0..15
    gK[t] = kbb + rk * 256 + ((sk ^ (rk & 15)) << 4);
    int rv = gg >> 3, sv = gg & 7;    // V row 0..127, slot 0..7
    gV[t] = vbb + rv * 4096 + ((sv ^ (rv & 7)) << 4);
  }

  const float SL2E = 0.08838834764831845f * 1.4426950408889634f;  // scale*log2(e)

  auto stageKV = [&](int kt, int buf) {
#pragma unroll
    for (int t = 0; t < 2; t++) {
      int gg = t * 512 + tid;
      gload16(gK[t] + (size_t)kt * 16384, lds + buf * 16384 + gg * 16);
      gload16(gV[t] + (size_t)kt * 128, lds + 32768 + buf * 16384 + gg * 16);
    }
  };

  auto run_qtile = [&](int qt) {
    const int qrow0 = qt * 128 + w * 16;
    bf16x8 qf[4];
#pragma unroll
    for (int c = 0; c < 4; c++) {
      bf16x8 raw = *(const bf16x8*)(qb + (size_t)(qrow0 + (lane & 15)) * 128 +
                                    c * 32 + ((lane >> 4) << 3));
#pragma unroll
      for (int e = 0; e < 8; e++) qf[c][e] = (__bf16)((float)raw[e] * SL2E);
    }
    float m[4], lsp[4];
    f32x4 o[8];
#pragma unroll
    for (int r = 0; r < 4; r++) { m[r] = -__builtin_inff(); lsp[r] = 0.f; }
#pragma unroll
    for (int n = 0; n < 8; n++) o[n] = (f32x4){0.f, 0.f, 0.f, 0.f};

    const int NKT = 2 * qt + 2;
    stageKV(0, 0);

    for (int kt = 0; kt < NKT; kt++) {
      const int cur = kt & 1;
      const char* Ks = lds + cur * 16384;
      const char* Vs = lds + 32768 + cur * 16384;
      if (kt < NKT - 1) {
        stageKV(kt + 1, cur ^ 1);
        asm volatile("s_waitcnt vmcnt(4)" ::: "memory");  // current tile landed
      } else {
        asm volatile("s_waitcnt vmcnt(0)" ::: "memory");
      }
      __builtin_amdgcn_s_barrier();

      f32x4 s[4];
      __builtin_amdgcn_s_setprio(1);
#pragma unroll
      for (int n = 0; n < 4; n++) {
        s[n] = (f32x4){0.f, 0.f, 0.f, 0.f};
#pragma unroll
        for (int c = 0; c < 4; c++) {
          int krow = n * 16 + (lane & 15);
          int c16 = c * 4 + (lane >> 4);
          bf16x8 kf = *(const bf16x8*)(Ks + krow * 256 + ((c16 ^ (krow & 15)) << 4));
          s[n] = __builtin_amdgcn_mfma_f32_16x16x32_bf16(qf[c], kf, s[n], 0, 0, 0);
        }
      }
      __builtin_amdgcn_s_setprio(0);

      if (kt * 64 + 63 > qrow0) {
#pragma unroll
        for (int r = 0; r < 4; r++) {
          const int qrow = qrow0 + ((lane >> 4) << 2) + r;
#pragma unroll
          for (int n = 0; n < 4; n++) {
            int col = kt * 64 + n * 16 + (lane & 15);
            if (col > qrow) s[n][r] = -__builtin_inff();
          }
        }
      }

      float tmx[4];
#pragma unroll
      for (int r = 0; r < 4; r++)
        tmx[r] = fmaxf(fmaxf(s[0][r], s[1][r]), fmaxf(s[2][r], s[3][r]));
      bool hot = (tmx[0] > m[0] + 8.f) | (tmx[1] > m[1] + 8.f) |
                 (tmx[2] > m[2] + 8.f) | (tmx[3] > m[3] + 8.f);
      if (__any(hot)) {
        float fc[4];
#pragma unroll
        for (int r = 0; r < 4; r++) {
          float gmx = tmx[r];
#pragma unroll
          for (int mk = 1; mk < 16; mk <<= 1) gmx = fmaxf(gmx, __shfl_xor(gmx, mk));
          float nm = fmaxf(m[r], gmx);
          fc[r] = __builtin_amdgcn_exp2f(m[r] - nm);
          m[r] = nm;
          lsp[r] *= fc[r];
        }
#pragma unroll
        for (int n = 0; n < 8; n++) {
          o[n][0] *= fc[0]; o[n][1] *= fc[1]; o[n][2] *= fc[2]; o[n][3] *= fc[3];
        }
      }

      float p[4][4];
#pragma unroll
      for (int r = 0; r < 4; r++) {
        float sum = 0.f;
#pragma unroll
        for (int n = 0; n < 4; n++) {
          float pv = __builtin_amdgcn_exp2f(s[n][r] - m[r]);
          p[n][r] = pv;
          sum += pv;
        }
        lsp[r] += sum;
      }

#pragma unroll
      for (int n = 0; n < 4; n++)
#pragma unroll
        for (int r = 0; r < 4; r++) {
          int prow = ((lane >> 4) << 2) + r;
          int col = n * 16 + (lane & 15);
          int ch = col >> 3;
          *(__bf16*)(Pw + prow * 128 + ((ch ^ (prow & 7)) << 4) + ((col & 7) << 1)) =
              (__bf16)p[n][r];
        }

      __builtin_amdgcn_s_setprio(1);
#pragma unroll
      for (int kk = 0; kk < 2; kk++) {
        int prow = lane & 15;
        int pc = kk * 4 + (lane >> 4);
        bf16x8 pf = *(const bf16x8*)(Pw + prow * 128 + ((pc ^ (prow & 7)) << 4));
#pragma unroll
        for (int n = 0; n < 8; n++) {
          int vr = n * 16 + (lane & 15);
          bf16x8 vf = *(const bf16x8*)(Vs + vr * 128 + ((pc ^ (vr & 7)) << 4));
          o[n] = __builtin_amdgcn_mfma_f32_16x16x32_bf16(pf, vf, o[n], 0, 0, 0);
        }
      }
      __builtin_amdgcn_s_setprio(0);
      __builtin_amdgcn_s_barrier();
    }

    float inv[4];
#pragma unroll
    for (int r = 0; r < 4; r++) {
      float ls = lsp[r];
#pragma unroll
      for (int mk = 1; mk < 16; mk <<= 1) ls += __shfl_xor(ls, mk);
      inv[r] = 1.0f / ls;
    }
#pragma unroll
    for (int n = 0; n < 8; n++)
#pragma unroll
      for (int r = 0; r < 4; r++) {
        int qrow = qrow0 + ((lane >> 4) << 2) + r;
        og[(size_t)(b * 2048 + qrow) * 2048 + h * 128 + n * 16 + (lane & 15)] =
            (__bf16)(o[n][r] * inv[r]);
      }
  };

  run_qtile(15 - (int)blockIdx.x);
  run_qtile((int)blockIdx.x);
}

// ---------------------------------------------------------------------------
extern "C" void kernel_launch(void* const* d_in, const int* in_sizes, int n_in,
                              void* d_out, int out_size, void* d_ws, size_t ws_size,
                              hipStream_t stream) {
  const float* x = (const float*)d_in[0];
  const float* w_qkv = (const float*)d_in[1];
  const float* w_out = (const float*)d_in[2];
  const float* w_fc = (const float*)d_in[3];
  const float* w_proj = (const float*)d_in[4];
  const float* g_in = (const float*)d_in[5];
  const float* g_ff = (const float*)d_in[6];
  float* out = (float*)d_out;
  char* ws = (char*)d_ws;

  constexpr size_t O_WQKV = 0;           // bf16 [6144][2048]
  constexpr size_t O_WOUT = 25165824;    // bf16 [2048][2048]
  constexpr size_t O_WFC = 33554432;     // bf16 [4096][2048]
  constexpr size_t O_WPROJ = 50331648;   // bf16 [2048][4096]
  constexpr size_t O_H = 67108864;       // bf16 [4096][2048]
  constexpr size_t O_QKV = 83886080;     // bf16 fcact [4096][4096]
  constexpr size_t O_Q = 134217728;      // bf16 [2][16][2048][128]
  constexpr size_t O_K = 150994944;
  constexpr size_t O_VT = 167772160;     // bf16 [2][16][128][2048]
  constexpr size_t O_ATTN = 185597952;   // bf16 [4096][2048]
  constexpr size_t O_X1 = 202375168;     // f32 [4096][2048]

  __bf16* wqkvT = (__bf16*)(ws + O_WQKV);
  __bf16* woutT = (__bf16*)(ws + O_WOUT);
  __bf16* wfcT = (__bf16*)(ws + O_WFC);
  __bf16* wprojT = (__bf16*)(ws + O_WPROJ);
  __bf16* h = (__bf16*)(ws + O_H);
  __bf16* fcact = (__bf16*)(ws + O_QKV);
  __bf16* qr = (__bf16*)(ws + O_Q);
  __bf16* kr = (__bf16*)(ws + O_K);
  __bf16* vt = (__bf16*)(ws + O_VT);
  __bf16* attn = (__bf16*)(ws + O_ATTN);
  float* x1 = (float*)(ws + O_X1);

  // all four weight transposes in one launch
  transpose_cvt_all<<<8192, 256, 0, stream>>>(w_qkv, w_out, w_fc, w_proj,
                                              wqkvT, woutT, wfcT, wprojT);
  // h = rmsnorm(x, g_in)
  rmsnorm_kernel<<<4096, 256, 0, stream>>>(x, g_in, h);
  // q,k (roped, on-the-fly sin/cos) + v^T from the qkv GEMM epilogue
  gemm_qkv<<<dim3(48, 32), 256, 0, stream>>>(h, wqkvT, qr, kr, vt, 2048);
  // attention (QBLK=128, balanced pairs)
  flash_attn<<<dim3(8, 16, 2), 512, 0, stream>>>(qr, kr, vt, attn);
  // x1 = x + attn @ w_out
  gemm_bt<1><<<dim3(16, 32), 256, 0, stream>>>(attn, woutT, (void*)x1, x, 4096, 2048, 2048);
  // h2 = rmsnorm(x1, g_ff)
  rmsnorm_kernel<<<4096, 256, 0, stream>>>(x1, g_ff, h);
  // fcact = gelu(h2 @ w_fc)  (256^2 8-phase, grid 16x16 = exactly 1 round)
  gemm256<2><<<dim3(16, 16), 512, 0, stream>>>(h, wfcT, (void*)fcact, nullptr, 4096, 4096, 2048);
  // out = x1 + fcact @ w_proj
  gemm_bt<1><<<dim3(16, 32), 256, 0, stream>>>(fcact, wprojT, (void*)out, x1, 4096, 2048, 4096);
}